// Round 2
// baseline (36967.703 us; speedup 1.0000x reference)
//
#include <hip/hip_runtime.h>
#include <stdint.h>

#define TT 12
#define NITERS 10
#define NCAND 1000
#define AD 6
#define BD 16
#define HD 200
#define ZD 30
#define NROWS 16000
#define NELEM 1152000u

// ws layout (float offsets). Total 5,337,552 floats = 21.35 MB.
#define OFF_WALL 0u           // [240][256] stacked [Wb;Ws;Wa] padded
#define OFF_BB   61440u       // [256]
#define OFF_WZ   61696u       // [200][32]
#define OFF_BZ   68096u       // [32]
#define OFF_WR   68128u       // [240]
#define OFF_MEAN 68368u       // [12][16][8]
#define OFF_STD  69904u       // [12][16][8]
#define OFF_S0   71440u       // [16][32] padded initial state
#define OFF_BCUR 71952u       // [16000][200]
#define OFF_SCUR 3271952u     // [16000][32]
#define OFF_ACT  3783952u     // [12][16000][8]
#define OFF_RET  5319952u     // [16000]
#define OFF_TOPK 5335952u     // int [16][100]

// ---------------- threefry2x32 (JAX-exact) ----------------
__host__ __device__ __forceinline__ uint32_t tf_rotl(uint32_t x, int r) {
  return (x << r) | (x >> (32 - r));
}
__host__ __device__ __forceinline__ void tf2x32(uint32_t k0, uint32_t k1,
                                                uint32_t& x0, uint32_t& x1) {
  uint32_t k2 = k0 ^ k1 ^ 0x1BD11BDAu;
  x0 += k0; x1 += k1;
  x0 += x1; x1 = tf_rotl(x1, 13); x1 ^= x0;
  x0 += x1; x1 = tf_rotl(x1, 15); x1 ^= x0;
  x0 += x1; x1 = tf_rotl(x1, 26); x1 ^= x0;
  x0 += x1; x1 = tf_rotl(x1,  6); x1 ^= x0;
  x0 += k1; x1 += k2 + 1u;
  x0 += x1; x1 = tf_rotl(x1, 17); x1 ^= x0;
  x0 += x1; x1 = tf_rotl(x1, 29); x1 ^= x0;
  x0 += x1; x1 = tf_rotl(x1, 16); x1 ^= x0;
  x0 += x1; x1 = tf_rotl(x1, 24); x1 ^= x0;
  x0 += k2; x1 += k0 + 2u;
  x0 += x1; x1 = tf_rotl(x1, 13); x1 ^= x0;
  x0 += x1; x1 = tf_rotl(x1, 15); x1 ^= x0;
  x0 += x1; x1 = tf_rotl(x1, 26); x1 ^= x0;
  x0 += x1; x1 = tf_rotl(x1,  6); x1 ^= x0;
  x0 += k0; x1 += k1 + 3u;
  x0 += x1; x1 = tf_rotl(x1, 17); x1 ^= x0;
  x0 += x1; x1 = tf_rotl(x1, 29); x1 ^= x0;
  x0 += x1; x1 = tf_rotl(x1, 16); x1 ^= x0;
  x0 += x1; x1 = tf_rotl(x1, 24); x1 ^= x0;
  x0 += k1; x1 += k2 + 4u;
  x0 += x1; x1 = tf_rotl(x1, 13); x1 ^= x0;
  x0 += x1; x1 = tf_rotl(x1, 15); x1 ^= x0;
  x0 += x1; x1 = tf_rotl(x1, 26); x1 ^= x0;
  x0 += x1; x1 = tf_rotl(x1,  6); x1 ^= x0;
  x0 += k2; x1 += k0 + 5u;
}

__device__ __forceinline__ float bits_to_normal(uint32_t bits) {
  uint32_t fb = (bits >> 9) | 0x3F800000u;
  float f = __uint_as_float(fb) - 1.0f;          // [0,1)
  float u = f * 2.0f - 0.99999994f;              // scale==2.0f exactly
  u = fmaxf(-0.99999994f, u);
  float w = -log1pf(-u * u);
  float p;
  if (w < 5.0f) {
    w = w - 2.5f;
    p = 2.81022636e-08f;
    p = fmaf(p, w, 3.43273939e-07f);
    p = fmaf(p, w, -3.5233877e-06f);
    p = fmaf(p, w, -4.39150654e-06f);
    p = fmaf(p, w, 0.00021858087f);
    p = fmaf(p, w, -0.00125372503f);
    p = fmaf(p, w, -0.00417768164f);
    p = fmaf(p, w, 0.246640727f);
    p = fmaf(p, w, 1.50140941f);
  } else {
    w = sqrtf(w) - 3.0f;
    p = -0.000200214257f;
    p = fmaf(p, w, 0.000100950558f);
    p = fmaf(p, w, 0.00134934322f);
    p = fmaf(p, w, -0.00367342844f);
    p = fmaf(p, w, 0.00573950773f);
    p = fmaf(p, w, -0.0076224613f);
    p = fmaf(p, w, 0.00943887047f);
    p = fmaf(p, w, 1.00167406f);
    p = fmaf(p, w, 2.83297682f);
  }
  return 1.41421354f * (p * u);
}

// ---------------- prep: pack weights, init mean/std, pad s0 ----------------
__global__ __launch_bounds__(256) void k_prep(const float* Wb, const float* Ws_,
                                              const float* Wa, const float* bb,
                                              const float* Wz, const float* bz,
                                              const float* Wr, const float* state,
                                              float* ws) {
  int i = blockIdx.x * 256 + threadIdx.x;
  if (i < 61440) {
    int k = i >> 8, c = i & 255;
    float v = 0.f;
    if (c < HD) {
      if (k < 200)      v = Wb[k * HD + c];
      else if (k < 230) v = Ws_[(k - 200) * HD + c];
      else if (k < 236) v = Wa[(k - 230) * HD + c];
    }
    ws[OFF_WALL + i] = v;
  } else if (i < 61696) {
    int c = i - 61440;
    ws[i] = (c < HD) ? bb[c] : 0.f;
  } else if (i < 68096) {
    int j = i - 61696; int k = j >> 5, z = j & 31;
    ws[i] = (z < ZD) ? Wz[k * ZD + z] : 0.f;
  } else if (i < 68128) {
    int z = i - 68096;
    ws[i] = (z < ZD) ? bz[z] : 0.f;
  } else if (i < 68368) {
    int k = i - 68128;
    ws[i] = (k < 230) ? Wr[k] : 0.f;
  } else if (i < 69904) {
    ws[i] = 0.f;   // mean
  } else if (i < 71440) {
    ws[i] = 1.f;   // std
  } else if (i < 71952) {
    int j = i - 71440; int b = j >> 5, z = j & 31;
    ws[i] = (z < ZD) ? state[b * ZD + z] : 0.f;
  }
}

// ---------------- actions = mean + std * normal(threefry) ----------------
__global__ __launch_bounds__(256) void k_actions(uint32_t k0, uint32_t k1, float* ws) {
  uint32_t idx = blockIdx.x * 256u + threadIdx.x;
  if (idx >= NELEM) return;
  uint32_t x0 = 0u, x1 = idx;
  tf2x32(k0, k1, x0, x1);
  float z = bits_to_normal(x0 ^ x1);
  uint32_t a = idx % 6u;  uint32_t q = idx / 6u;
  uint32_t c = q % 1000u; uint32_t q2 = q / 1000u;
  uint32_t b = q2 % 16u;  uint32_t t = q2 / 16u;
  uint32_t mi = (t * 16u + b) * 8u + a;
  float m = ws[OFF_MEAN + mi];
  float s = ws[OFF_STD + mi];
  ws[OFF_ACT + ((size_t)t * NROWS + b * 1000u + c) * 8u + a] = fmaf(s, z, m);
}

// ---------------- fused rollout step (16 rows/block, 4 rows/wave) ----------------
__global__ __launch_bounds__(256, 4) void k_step(float* __restrict__ ws,
                                                 const float* __restrict__ belief,
                                                 const float* __restrict__ br, int t) {
  __shared__ float bsh[16][204];       // b_new tile
  __shared__ float sc2[8][16][33];     // stage-2 partials (+rew at [30])

  const int tid = threadIdx.x;
  const int wv = tid >> 6;
  const int ln = tid & 63;
  const int row0 = blockIdx.x * 16 + wv * 4;
  const int c0 = ln * 4;
  const bool colok = (c0 < HD);

  const float* __restrict__ Wall = ws + OFF_WALL;
  float* __restrict__ bcur = ws + OFF_BCUR;
  float* __restrict__ scur = ws + OFF_SCUR;
  const float* __restrict__ actp = ws + OFF_ACT + (size_t)t * NROWS * 8;

  // per-row x/s source pointers (t==0 reads inputs directly)
  const float* xp[4]; const float* sp[4];
#pragma unroll
  for (int r = 0; r < 4; ++r) {
    uint32_t row = row0 + r;
    if (t == 0) {
      uint32_t b = row / 1000u;
      xp[r] = belief + (size_t)b * HD;
      sp[r] = ws + OFF_S0 + (size_t)b * 32;
    } else {
      xp[r] = bcur + (size_t)row * HD;
      sp[r] = scur + (size_t)row * 32;
    }
  }

  float acc[4][4];
  {
    float bbv[4];
    *(float4*)bbv = *(const float4*)(ws + OFF_BB + c0);
#pragma unroll
    for (int r = 0; r < 4; ++r) {
      acc[r][0] = bbv[0]; acc[r][1] = bbv[1]; acc[r][2] = bbv[2]; acc[r][3] = bbv[3];
    }
  }

  // ---- region A: k in [0,200) ----
#pragma unroll 2
  for (int k = 0; k < 200; k += 4) {
    float xv[4][4];
#pragma unroll
    for (int r = 0; r < 4; ++r)
      *(float4*)xv[r] = *(const float4*)(xp[r] + k);
#pragma unroll
    for (int i = 0; i < 4; ++i) {
      float wv4[4];
      *(float4*)wv4 = *(const float4*)(Wall + (size_t)(k + i) * 256 + c0);
#pragma unroll
      for (int r = 0; r < 4; ++r) {
        const float xs = xv[r][i];
        acc[r][0] = fmaf(xs, wv4[0], acc[r][0]);
        acc[r][1] = fmaf(xs, wv4[1], acc[r][1]);
        acc[r][2] = fmaf(xs, wv4[2], acc[r][2]);
        acc[r][3] = fmaf(xs, wv4[3], acc[r][3]);
      }
    }
  }
  // ---- region B: k in [200,230) ----
#pragma unroll
  for (int kb = 0; kb < 28; kb += 4) {
    float xv[4][4];
#pragma unroll
    for (int r = 0; r < 4; ++r)
      *(float4*)xv[r] = *(const float4*)(sp[r] + kb);
#pragma unroll
    for (int i = 0; i < 4; ++i) {
      float wv4[4];
      *(float4*)wv4 = *(const float4*)(Wall + (size_t)(200 + kb + i) * 256 + c0);
#pragma unroll
      for (int r = 0; r < 4; ++r) {
        const float xs = xv[r][i];
        acc[r][0] = fmaf(xs, wv4[0], acc[r][0]);
        acc[r][1] = fmaf(xs, wv4[1], acc[r][1]);
        acc[r][2] = fmaf(xs, wv4[2], acc[r][2]);
        acc[r][3] = fmaf(xs, wv4[3], acc[r][3]);
      }
    }
  }
  {
    float xv[4][2];
#pragma unroll
    for (int r = 0; r < 4; ++r)
      *(float2*)xv[r] = *(const float2*)(sp[r] + 28);
#pragma unroll
    for (int i = 0; i < 2; ++i) {
      float wv4[4];
      *(float4*)wv4 = *(const float4*)(Wall + (size_t)(228 + i) * 256 + c0);
#pragma unroll
      for (int r = 0; r < 4; ++r) {
        const float xs = xv[r][i];
        acc[r][0] = fmaf(xs, wv4[0], acc[r][0]);
        acc[r][1] = fmaf(xs, wv4[1], acc[r][1]);
        acc[r][2] = fmaf(xs, wv4[2], acc[r][2]);
        acc[r][3] = fmaf(xs, wv4[3], acc[r][3]);
      }
    }
  }
  // ---- region C: k in [230,236) from actions ----
  {
    float xa[4][4], xa2[4][2];
#pragma unroll
    for (int r = 0; r < 4; ++r) {
      *(float4*)xa[r]  = *(const float4*)(actp + (size_t)(row0 + r) * 8);
      *(float2*)xa2[r] = *(const float2*)(actp + (size_t)(row0 + r) * 8 + 4);
    }
#pragma unroll
    for (int i = 0; i < 4; ++i) {
      float wv4[4];
      *(float4*)wv4 = *(const float4*)(Wall + (size_t)(230 + i) * 256 + c0);
#pragma unroll
      for (int r = 0; r < 4; ++r) {
        const float xs = xa[r][i];
        acc[r][0] = fmaf(xs, wv4[0], acc[r][0]);
        acc[r][1] = fmaf(xs, wv4[1], acc[r][1]);
        acc[r][2] = fmaf(xs, wv4[2], acc[r][2]);
        acc[r][3] = fmaf(xs, wv4[3], acc[r][3]);
      }
    }
#pragma unroll
    for (int i = 0; i < 2; ++i) {
      float wv4[4];
      *(float4*)wv4 = *(const float4*)(Wall + (size_t)(234 + i) * 256 + c0);
#pragma unroll
      for (int r = 0; r < 4; ++r) {
        const float xs = xa2[r][i];
        acc[r][0] = fmaf(xs, wv4[0], acc[r][0]);
        acc[r][1] = fmaf(xs, wv4[1], acc[r][1]);
        acc[r][2] = fmaf(xs, wv4[2], acc[r][2]);
        acc[r][3] = fmaf(xs, wv4[3], acc[r][3]);
      }
    }
  }

  // tanh + write b_new (global + LDS)
  const int lr0 = wv * 4;
#pragma unroll
  for (int r = 0; r < 4; ++r) {
    float h[4];
    h[0] = tanhf(acc[r][0]); h[1] = tanhf(acc[r][1]);
    h[2] = tanhf(acc[r][2]); h[3] = tanhf(acc[r][3]);
    if (colok) {
      *(float4*)(bcur + (size_t)(row0 + r) * HD + c0) = *(float4*)h;
      *(float4*)&bsh[lr0 + r][c0] = *(float4*)h;
    }
  }
  __syncthreads();

  // ---- stage 2: 16 rows x 8 k-parts on 128 threads ----
  const float* Wzp = ws + OFF_WZ;
  const float* Wrp = ws + OFF_WR;
  if (tid < 128) {
    const int lrow = tid & 15;
    const int part = tid >> 4;         // 0..7, 25 k each
    float a2[30];
#pragma unroll
    for (int z = 0; z < 30; ++z) a2[z] = 0.f;
    float rew = 0.f;
    const int kbeg = part * 25;
    for (int k = kbeg; k < kbeg + 25; ++k) {
      const float xb = bsh[lrow][k];
      rew = fmaf(xb, Wrp[k], rew);
#pragma unroll
      for (int zz = 0; zz < 7; ++zz) {
        float wz4[4];
        *(float4*)wz4 = *(const float4*)(Wzp + (size_t)k * 32 + zz * 4);
        a2[zz * 4 + 0] = fmaf(xb, wz4[0], a2[zz * 4 + 0]);
        a2[zz * 4 + 1] = fmaf(xb, wz4[1], a2[zz * 4 + 1]);
        a2[zz * 4 + 2] = fmaf(xb, wz4[2], a2[zz * 4 + 2]);
        a2[zz * 4 + 3] = fmaf(xb, wz4[3], a2[zz * 4 + 3]);
      }
      {
        float wz2[2];
        *(float2*)wz2 = *(const float2*)(Wzp + (size_t)k * 32 + 28);
        a2[28] = fmaf(xb, wz2[0], a2[28]);
        a2[29] = fmaf(xb, wz2[1], a2[29]);
      }
    }
#pragma unroll
    for (int z = 0; z < 30; ++z) sc2[part][lrow][z] = a2[z];
    sc2[part][lrow][30] = rew;
  }
  __syncthreads();

  // ---- final: wave 0, lane = lrow + 16*zq ----
  if (tid < 64) {
    const int lrow = tid & 15;
    const int zq = tid >> 4;           // 0..3
    const int grow = blockIdx.x * 16 + lrow;
    const float* bzp = ws + OFF_BZ;
    float rews = 0.f;
    const int z0 = zq * 8;
    const int zn = (zq == 3) ? 6 : 8;
    for (int j = 0; j < zn; ++j) {
      const int z = z0 + j;
      float v = bzp[z];
#pragma unroll
      for (int q = 0; q < 8; ++q) v += sc2[q][lrow][z];
      float s = tanhf(v);
      scur[(size_t)grow * 32 + z] = s;
      rews = fmaf(s, Wrp[200 + z], rews);
    }
    if (zq == 3) {
#pragma unroll
      for (int q = 0; q < 8; ++q) rews += sc2[q][lrow][30];
    }
    rews += __shfl_xor(rews, 16, 64);
    rews += __shfl_xor(rews, 32, 64);
    if (zq == 0) {
      float prev = (t == 0) ? 0.f : ws[OFF_RET + grow];
      ws[OFF_RET + grow] = prev + rews + br[0];
    }
  }
}

// ---------------- top-k via full bitonic sort (desc, ties by index) ----------------
__global__ __launch_bounds__(1024) void k_topk(float* ws) {
  __shared__ float sv[1024];
  __shared__ int si[1024];
  const int b = blockIdx.x, tid = threadIdx.x;
  const float* ret = ws + OFF_RET + b * 1000;
  sv[tid] = (tid < 1000) ? ret[tid] : -3.0e38f;
  si[tid] = tid;
  __syncthreads();
  for (int k = 2; k <= 1024; k <<= 1) {
    for (int j = k >> 1; j > 0; j >>= 1) {
      int ixj = tid ^ j;
      if (ixj > tid) {
        float v1 = sv[tid], v2 = sv[ixj];
        int i1 = si[tid], i2 = si[ixj];
        bool gt = (v1 < v2) || (v1 == v2 && i1 > i2);
        bool up = ((tid & k) == 0);
        if (up ? gt : !gt) {
          sv[tid] = v2; sv[ixj] = v1;
          si[tid] = i2; si[ixj] = i1;
        }
      }
      __syncthreads();
    }
  }
  int* topk = (int*)(ws + OFF_TOPK);
  if (tid < 100) topk[b * 100 + tid] = si[tid];
}

// ---------------- mean/std over elites: one wave per (t,b,a) ----------------
__global__ __launch_bounds__(256) void k_meanstd(float* ws) {
  const int g = blockIdx.x * 4 + (threadIdx.x >> 6);  // 0..1151
  const int ln = threadIdx.x & 63;
  const int t = g / 96; const int rem = g - t * 96;
  const int b = rem / 6; const int a = rem - b * 6;
  const int* topk = (const int*)(ws + OFF_TOPK) + b * 100;
  const float* act = ws + OFF_ACT + (size_t)t * NROWS * 8;
  const bool h2 = (ln < 36);
  int c1 = topk[ln];
  float x1 = act[((size_t)b * 1000 + c1) * 8 + a];
  float x2 = 0.f;
  if (h2) { int cc = topk[ln + 64]; x2 = act[((size_t)b * 1000 + cc) * 8 + a]; }
  float s = x1 + x2;
#pragma unroll
  for (int m = 1; m < 64; m <<= 1) s += __shfl_xor(s, m, 64);
  const float mean = s / 100.0f;
  float d = x1 - mean; float qq = d * d;
  if (h2) { float d2 = x2 - mean; qq += d2 * d2; }
#pragma unroll
  for (int m = 1; m < 64; m <<= 1) qq += __shfl_xor(qq, m, 64);
  if (ln == 0) {
    ws[OFF_MEAN + ((size_t)t * 16 + b) * 8 + a] = mean;
    ws[OFF_STD  + ((size_t)t * 16 + b) * 8 + a] = sqrtf(qq / 100.0f);
  }
}

__global__ void k_out(const float* ws, float* out) {
  int i = threadIdx.x;
  if (i < 96) out[i] = ws[OFF_MEAN + (i / 6) * 8 + (i % 6)];
}

extern "C" void kernel_launch(void* const* d_in, const int* in_sizes, int n_in,
                              void* d_out, int out_size, void* d_ws, size_t ws_size,
                              hipStream_t stream) {
  const float* belief = (const float*)d_in[0];
  const float* state  = (const float*)d_in[1];
  const float* Wb  = (const float*)d_in[2];
  const float* Ws_ = (const float*)d_in[3];
  const float* Wa  = (const float*)d_in[4];
  const float* bb  = (const float*)d_in[5];
  const float* Wz  = (const float*)d_in[6];
  const float* bz  = (const float*)d_in[7];
  const float* Wr  = (const float*)d_in[8];
  const float* br  = (const float*)d_in[9];
  float* ws = (float*)d_ws;   // needs ~21.4 MB

  k_prep<<<282, 256, 0, stream>>>(Wb, Ws_, Wa, bb, Wz, bz, Wr, state, ws);

  for (int it = 0; it < NITERS; ++it) {
    uint32_t f0 = 0u, f1 = (uint32_t)it;
    tf2x32(0u, 42u, f0, f1);
    k_actions<<<4500, 256, 0, stream>>>(f0, f1, ws);
    for (int t = 0; t < TT; ++t)
      k_step<<<1000, 256, 0, stream>>>(ws, belief, br, t);
    k_topk<<<16, 1024, 0, stream>>>(ws);
    k_meanstd<<<288, 256, 0, stream>>>(ws);
  }
  k_out<<<1, 128, 0, stream>>>(ws, (float*)d_out);
}

// Round 3
// 9402.416 us; speedup vs baseline: 3.9317x; 3.9317x over previous
//
#include <hip/hip_runtime.h>
#include <stdint.h>

#define TT 12
#define NITERS 10
#define NCAND 1000
#define AD 6
#define BD 16
#define HD 200
#define ZD 30
#define NROWS 16000
#define NELEM 1152000u

// ws layout (float offsets).
#define OFF_WALL 0u           // [240][256] stacked [Wb;Ws;Wa] padded
#define OFF_BB   61440u       // [256]
#define OFF_WZ   61696u       // [200][32]
#define OFF_BZ   68096u       // [32]
#define OFF_WR   68128u       // [240]
#define OFF_MEAN 68368u       // [12][16][8]
#define OFF_STD  69904u       // [12][16][8]
#define OFF_ACT  3783952u     // [12][16000][8]
#define OFF_RET  5319952u     // [16000]
#define OFF_TOPK 5335952u     // int [16][100]

// ---------------- threefry2x32 (JAX-exact) ----------------
__host__ __device__ __forceinline__ uint32_t tf_rotl(uint32_t x, int r) {
  return (x << r) | (x >> (32 - r));
}
__host__ __device__ __forceinline__ void tf2x32(uint32_t k0, uint32_t k1,
                                                uint32_t& x0, uint32_t& x1) {
  uint32_t k2 = k0 ^ k1 ^ 0x1BD11BDAu;
  x0 += k0; x1 += k1;
  x0 += x1; x1 = tf_rotl(x1, 13); x1 ^= x0;
  x0 += x1; x1 = tf_rotl(x1, 15); x1 ^= x0;
  x0 += x1; x1 = tf_rotl(x1, 26); x1 ^= x0;
  x0 += x1; x1 = tf_rotl(x1,  6); x1 ^= x0;
  x0 += k1; x1 += k2 + 1u;
  x0 += x1; x1 = tf_rotl(x1, 17); x1 ^= x0;
  x0 += x1; x1 = tf_rotl(x1, 29); x1 ^= x0;
  x0 += x1; x1 = tf_rotl(x1, 16); x1 ^= x0;
  x0 += x1; x1 = tf_rotl(x1, 24); x1 ^= x0;
  x0 += k2; x1 += k0 + 2u;
  x0 += x1; x1 = tf_rotl(x1, 13); x1 ^= x0;
  x0 += x1; x1 = tf_rotl(x1, 15); x1 ^= x0;
  x0 += x1; x1 = tf_rotl(x1, 26); x1 ^= x0;
  x0 += x1; x1 = tf_rotl(x1,  6); x1 ^= x0;
  x0 += k0; x1 += k1 + 3u;
  x0 += x1; x1 = tf_rotl(x1, 17); x1 ^= x0;
  x0 += x1; x1 = tf_rotl(x1, 29); x1 ^= x0;
  x0 += x1; x1 = tf_rotl(x1, 16); x1 ^= x0;
  x0 += x1; x1 = tf_rotl(x1, 24); x1 ^= x0;
  x0 += k1; x1 += k2 + 4u;
  x0 += x1; x1 = tf_rotl(x1, 13); x1 ^= x0;
  x0 += x1; x1 = tf_rotl(x1, 15); x1 ^= x0;
  x0 += x1; x1 = tf_rotl(x1, 26); x1 ^= x0;
  x0 += x1; x1 = tf_rotl(x1,  6); x1 ^= x0;
  x0 += k2; x1 += k0 + 5u;
}

__device__ __forceinline__ float bits_to_normal(uint32_t bits) {
  uint32_t fb = (bits >> 9) | 0x3F800000u;
  float f = __uint_as_float(fb) - 1.0f;          // [0,1)
  float u = f * 2.0f - 0.99999994f;              // scale==2.0f exactly
  u = fmaxf(-0.99999994f, u);
  float w = -log1pf(-u * u);
  float p;
  if (w < 5.0f) {
    w = w - 2.5f;
    p = 2.81022636e-08f;
    p = fmaf(p, w, 3.43273939e-07f);
    p = fmaf(p, w, -3.5233877e-06f);
    p = fmaf(p, w, -4.39150654e-06f);
    p = fmaf(p, w, 0.00021858087f);
    p = fmaf(p, w, -0.00125372503f);
    p = fmaf(p, w, -0.00417768164f);
    p = fmaf(p, w, 0.246640727f);
    p = fmaf(p, w, 1.50140941f);
  } else {
    w = sqrtf(w) - 3.0f;
    p = -0.000200214257f;
    p = fmaf(p, w, 0.000100950558f);
    p = fmaf(p, w, 0.00134934322f);
    p = fmaf(p, w, -0.00367342844f);
    p = fmaf(p, w, 0.00573950773f);
    p = fmaf(p, w, -0.0076224613f);
    p = fmaf(p, w, 0.00943887047f);
    p = fmaf(p, w, 1.00167406f);
    p = fmaf(p, w, 2.83297682f);
  }
  return 1.41421354f * (p * u);
}

// ---------------- prep: pack weights, init mean/std ----------------
__global__ __launch_bounds__(256) void k_prep(const float* Wb, const float* Ws_,
                                              const float* Wa, const float* bb,
                                              const float* Wz, const float* bz,
                                              const float* Wr, float* ws) {
  int i = blockIdx.x * 256 + threadIdx.x;
  if (i < 61440) {
    int k = i >> 8, c = i & 255;
    float v = 0.f;
    if (c < HD) {
      if (k < 200)      v = Wb[k * HD + c];
      else if (k < 230) v = Ws_[(k - 200) * HD + c];
      else if (k < 236) v = Wa[(k - 230) * HD + c];
    }
    ws[OFF_WALL + i] = v;
  } else if (i < 61696) {
    int c = i - 61440;
    ws[i] = (c < HD) ? bb[c] : 0.f;
  } else if (i < 68096) {
    int j = i - 61696; int k = j >> 5, z = j & 31;
    ws[i] = (z < ZD) ? Wz[k * ZD + z] : 0.f;
  } else if (i < 68128) {
    int z = i - 68096;
    ws[i] = (z < ZD) ? bz[z] : 0.f;
  } else if (i < 68368) {
    int k = i - 68128;
    ws[i] = (k < 230) ? Wr[k] : 0.f;
  } else if (i < 69904) {
    ws[i] = 0.f;   // mean
  } else if (i < 71440) {
    ws[i] = 1.f;   // std
  }
}

// ---------------- actions = mean + std * normal(threefry) ----------------
__global__ __launch_bounds__(256) void k_actions(uint32_t k0, uint32_t k1, float* ws) {
  uint32_t idx = blockIdx.x * 256u + threadIdx.x;
  if (idx >= NELEM) return;
  uint32_t x0 = 0u, x1 = idx;
  tf2x32(k0, k1, x0, x1);
  float z = bits_to_normal(x0 ^ x1);
  uint32_t a = idx % 6u;  uint32_t q = idx / 6u;
  uint32_t c = q % 1000u; uint32_t q2 = q / 1000u;
  uint32_t b = q2 % 16u;  uint32_t t = q2 / 16u;
  uint32_t mi = (t * 16u + b) * 8u + a;
  float m = ws[OFF_MEAN + mi];
  float s = ws[OFF_STD + mi];
  ws[OFF_ACT + ((size_t)t * NROWS + b * 1000u + c) * 8u + a] = fmaf(s, z, m);
}

// ---------------- full 12-step rollout, one launch ----------------
// 16 rows/block, 4 rows/wave. b,s live in LDS across all 12 steps.
// stage1: h = tanh([b|s|a_t] @ W_all + bb)   (K=236, N=200)
// stage2: s_new = tanh(h @ Wz + bz); ret += [h,s_new].Wr + br
__global__ __launch_bounds__(256) void k_roll(float* __restrict__ ws,
                                              const float* __restrict__ belief,
                                              const float* __restrict__ state,
                                              const float* __restrict__ br) {
  __shared__ float xls[16][204];       // b_cur / b_new (f32)
  __shared__ float sls[16][32];        // s_cur / s_new
  __shared__ float sc2[8][16][33];     // stage-2 partials (+rew at [30])

  const int tid = threadIdx.x;
  const int wv = tid >> 6;
  const int ln = tid & 63;
  const int c0 = ln * 4;
  const bool colok = (c0 < HD);
  const int row0g = blockIdx.x * 16;   // global row base of block
  const int lr0 = wv * 4;              // local row base of wave

  // init LDS from inputs (broadcast per batch)
  for (int idx = tid; idx < 16 * HD; idx += 256) {
    int r = idx / HD, c = idx - r * HD;
    xls[r][c] = belief[(size_t)((row0g + r) / 1000) * HD + c];
  }
  for (int idx = tid; idx < 16 * 32; idx += 256) {
    int r = idx >> 5, z = idx & 31;
    sls[r][z] = (z < ZD) ? state[(size_t)((row0g + r) / 1000) * ZD + z] : 0.f;
  }
  const float br0 = br[0];
  float ret_acc = 0.f;
  __syncthreads();

  const float* __restrict__ Wall = ws + OFF_WALL;
  const float* __restrict__ Wzp  = ws + OFF_WZ;
  const float* __restrict__ Wrp  = ws + OFF_WR;
  const float* __restrict__ bzp  = ws + OFF_BZ;

  for (int t = 0; t < TT; ++t) {
    const float* __restrict__ actp =
        ws + OFF_ACT + (size_t)t * NROWS * 8 + (size_t)row0g * 8;

    float acc[4][4];
    {
      float bbv[4];
      *(float4*)bbv = *(const float4*)(ws + OFF_BB + c0);
#pragma unroll
      for (int r = 0; r < 4; ++r) {
        acc[r][0] = bbv[0]; acc[r][1] = bbv[1]; acc[r][2] = bbv[2]; acc[r][3] = bbv[3];
      }
    }

    // ---- region A: k in [0,200) from xls (wave-uniform LDS broadcast) ----
#pragma unroll 2
    for (int k = 0; k < 200; k += 4) {
      float xv[4][4];
#pragma unroll
      for (int r = 0; r < 4; ++r)
        *(float4*)xv[r] = *(const float4*)&xls[lr0 + r][k];
#pragma unroll
      for (int i = 0; i < 4; ++i) {
        float wv4[4];
        *(float4*)wv4 = *(const float4*)(Wall + (size_t)(k + i) * 256 + c0);
#pragma unroll
        for (int r = 0; r < 4; ++r) {
          const float xs = xv[r][i];
          acc[r][0] = fmaf(xs, wv4[0], acc[r][0]);
          acc[r][1] = fmaf(xs, wv4[1], acc[r][1]);
          acc[r][2] = fmaf(xs, wv4[2], acc[r][2]);
          acc[r][3] = fmaf(xs, wv4[3], acc[r][3]);
        }
      }
    }
    // ---- region B: k in [200,230) from sls ----
#pragma unroll
    for (int kb = 0; kb < 28; kb += 4) {
      float xv[4][4];
#pragma unroll
      for (int r = 0; r < 4; ++r)
        *(float4*)xv[r] = *(const float4*)&sls[lr0 + r][kb];
#pragma unroll
      for (int i = 0; i < 4; ++i) {
        float wv4[4];
        *(float4*)wv4 = *(const float4*)(Wall + (size_t)(200 + kb + i) * 256 + c0);
#pragma unroll
        for (int r = 0; r < 4; ++r) {
          const float xs = xv[r][i];
          acc[r][0] = fmaf(xs, wv4[0], acc[r][0]);
          acc[r][1] = fmaf(xs, wv4[1], acc[r][1]);
          acc[r][2] = fmaf(xs, wv4[2], acc[r][2]);
          acc[r][3] = fmaf(xs, wv4[3], acc[r][3]);
        }
      }
    }
    {
      float xv[4][2];
#pragma unroll
      for (int r = 0; r < 4; ++r)
        *(float2*)xv[r] = *(const float2*)&sls[lr0 + r][28];
#pragma unroll
      for (int i = 0; i < 2; ++i) {
        float wv4[4];
        *(float4*)wv4 = *(const float4*)(Wall + (size_t)(228 + i) * 256 + c0);
#pragma unroll
        for (int r = 0; r < 4; ++r) {
          const float xs = xv[r][i];
          acc[r][0] = fmaf(xs, wv4[0], acc[r][0]);
          acc[r][1] = fmaf(xs, wv4[1], acc[r][1]);
          acc[r][2] = fmaf(xs, wv4[2], acc[r][2]);
          acc[r][3] = fmaf(xs, wv4[3], acc[r][3]);
        }
      }
    }
    // ---- region C: k in [230,236) from actions (global, wave-uniform) ----
    {
      float xa[4][4], xa2[4][2];
#pragma unroll
      for (int r = 0; r < 4; ++r) {
        *(float4*)xa[r]  = *(const float4*)(actp + (size_t)(lr0 + r) * 8);
        *(float2*)xa2[r] = *(const float2*)(actp + (size_t)(lr0 + r) * 8 + 4);
      }
#pragma unroll
      for (int i = 0; i < 4; ++i) {
        float wv4[4];
        *(float4*)wv4 = *(const float4*)(Wall + (size_t)(230 + i) * 256 + c0);
#pragma unroll
        for (int r = 0; r < 4; ++r) {
          const float xs = xa[r][i];
          acc[r][0] = fmaf(xs, wv4[0], acc[r][0]);
          acc[r][1] = fmaf(xs, wv4[1], acc[r][1]);
          acc[r][2] = fmaf(xs, wv4[2], acc[r][2]);
          acc[r][3] = fmaf(xs, wv4[3], acc[r][3]);
        }
      }
#pragma unroll
      for (int i = 0; i < 2; ++i) {
        float wv4[4];
        *(float4*)wv4 = *(const float4*)(Wall + (size_t)(234 + i) * 256 + c0);
#pragma unroll
        for (int r = 0; r < 4; ++r) {
          const float xs = xa2[r][i];
          acc[r][0] = fmaf(xs, wv4[0], acc[r][0]);
          acc[r][1] = fmaf(xs, wv4[1], acc[r][1]);
          acc[r][2] = fmaf(xs, wv4[2], acc[r][2]);
          acc[r][3] = fmaf(xs, wv4[3], acc[r][3]);
        }
      }
    }

    // tanh + write b_new to xls (own rows only -> no cross-wave hazard yet)
#pragma unroll
    for (int r = 0; r < 4; ++r) {
      float h[4];
      h[0] = tanhf(acc[r][0]); h[1] = tanhf(acc[r][1]);
      h[2] = tanhf(acc[r][2]); h[3] = tanhf(acc[r][3]);
      if (colok) *(float4*)&xls[lr0 + r][c0] = *(float4*)h;
    }
    __syncthreads();   // B1: xls complete before cross-wave stage-2 reads

    // ---- stage 2 partial: 16 rows x 8 k-parts on 128 threads ----
    if (tid < 128) {
      const int lrow = tid & 15;
      const int part = tid >> 4;       // 0..7, 25 k each
      float a2[30];
#pragma unroll
      for (int z = 0; z < 30; ++z) a2[z] = 0.f;
      float rew = 0.f;
      const int kbeg = part * 25;
      for (int k = kbeg; k < kbeg + 25; ++k) {
        const float xb = xls[lrow][k];
        rew = fmaf(xb, Wrp[k], rew);
#pragma unroll
        for (int zz = 0; zz < 7; ++zz) {
          float wz4[4];
          *(float4*)wz4 = *(const float4*)(Wzp + (size_t)k * 32 + zz * 4);
          a2[zz * 4 + 0] = fmaf(xb, wz4[0], a2[zz * 4 + 0]);
          a2[zz * 4 + 1] = fmaf(xb, wz4[1], a2[zz * 4 + 1]);
          a2[zz * 4 + 2] = fmaf(xb, wz4[2], a2[zz * 4 + 2]);
          a2[zz * 4 + 3] = fmaf(xb, wz4[3], a2[zz * 4 + 3]);
        }
        {
          float wz2[2];
          *(float2*)wz2 = *(const float2*)(Wzp + (size_t)k * 32 + 28);
          a2[28] = fmaf(xb, wz2[0], a2[28]);
          a2[29] = fmaf(xb, wz2[1], a2[29]);
        }
      }
#pragma unroll
      for (int z = 0; z < 30; ++z) sc2[part][lrow][z] = a2[z];
      sc2[part][lrow][30] = rew;
    }
    __syncthreads();   // B2: sc2 complete

    // ---- stage 2 final: wave 0, lane = lrow + 16*zq ----
    if (tid < 64) {
      const int lrow = tid & 15;
      const int zq = tid >> 4;         // 0..3
      float rews = 0.f;
      const int z0 = zq * 8;
      const int zn = (zq == 3) ? 6 : 8;
      for (int j = 0; j < zn; ++j) {
        const int z = z0 + j;
        float v = bzp[z];
#pragma unroll
        for (int q = 0; q < 8; ++q) v += sc2[q][lrow][z];
        float s = tanhf(v);
        sls[lrow][z] = s;
        rews = fmaf(s, Wrp[200 + z], rews);
      }
      if (zq == 3) {
#pragma unroll
        for (int q = 0; q < 8; ++q) rews += sc2[q][lrow][30];
      }
      rews += __shfl_xor(rews, 16, 64);
      rews += __shfl_xor(rews, 32, 64);
      ret_acc += rews + br0;           // valid at all tid<64; used at tid<16
    }
    __syncthreads();   // B3: sls ready for next t
  }

  if (tid < 16) ws[OFF_RET + row0g + tid] = ret_acc;
}

// ---------------- top-k via full bitonic sort (desc, ties by index) ----------------
__global__ __launch_bounds__(1024) void k_topk(float* ws) {
  __shared__ float sv[1024];
  __shared__ int si[1024];
  const int b = blockIdx.x, tid = threadIdx.x;
  const float* ret = ws + OFF_RET + b * 1000;
  sv[tid] = (tid < 1000) ? ret[tid] : -3.0e38f;
  si[tid] = tid;
  __syncthreads();
  for (int k = 2; k <= 1024; k <<= 1) {
    for (int j = k >> 1; j > 0; j >>= 1) {
      int ixj = tid ^ j;
      if (ixj > tid) {
        float v1 = sv[tid], v2 = sv[ixj];
        int i1 = si[tid], i2 = si[ixj];
        bool gt = (v1 < v2) || (v1 == v2 && i1 > i2);
        bool up = ((tid & k) == 0);
        if (up ? gt : !gt) {
          sv[tid] = v2; sv[ixj] = v1;
          si[tid] = i2; si[ixj] = i1;
        }
      }
      __syncthreads();
    }
  }
  int* topk = (int*)(ws + OFF_TOPK);
  if (tid < 100) topk[b * 100 + tid] = si[tid];
}

// ---------------- mean/std over elites: one wave per (t,b,a) ----------------
__global__ __launch_bounds__(256) void k_meanstd(float* ws) {
  const int g = blockIdx.x * 4 + (threadIdx.x >> 6);  // 0..1151
  const int ln = threadIdx.x & 63;
  const int t = g / 96; const int rem = g - t * 96;
  const int b = rem / 6; const int a = rem - b * 6;
  const int* topk = (const int*)(ws + OFF_TOPK) + b * 100;
  const float* act = ws + OFF_ACT + (size_t)t * NROWS * 8;
  const bool h2 = (ln < 36);
  int c1 = topk[ln];
  float x1 = act[((size_t)b * 1000 + c1) * 8 + a];
  float x2 = 0.f;
  if (h2) { int cc = topk[ln + 64]; x2 = act[((size_t)b * 1000 + cc) * 8 + a]; }
  float s = x1 + x2;
#pragma unroll
  for (int m = 1; m < 64; m <<= 1) s += __shfl_xor(s, m, 64);
  const float mean = s / 100.0f;
  float d = x1 - mean; float qq = d * d;
  if (h2) { float d2 = x2 - mean; qq += d2 * d2; }
#pragma unroll
  for (int m = 1; m < 64; m <<= 1) qq += __shfl_xor(qq, m, 64);
  if (ln == 0) {
    ws[OFF_MEAN + ((size_t)t * 16 + b) * 8 + a] = mean;
    ws[OFF_STD  + ((size_t)t * 16 + b) * 8 + a] = sqrtf(qq / 100.0f);
  }
}

__global__ void k_out(const float* ws, float* out) {
  int i = threadIdx.x;
  if (i < 96) out[i] = ws[OFF_MEAN + (i / 6) * 8 + (i % 6)];
}

extern "C" void kernel_launch(void* const* d_in, const int* in_sizes, int n_in,
                              void* d_out, int out_size, void* d_ws, size_t ws_size,
                              hipStream_t stream) {
  const float* belief = (const float*)d_in[0];
  const float* state  = (const float*)d_in[1];
  const float* Wb  = (const float*)d_in[2];
  const float* Ws_ = (const float*)d_in[3];
  const float* Wa  = (const float*)d_in[4];
  const float* bb  = (const float*)d_in[5];
  const float* Wz  = (const float*)d_in[6];
  const float* bz  = (const float*)d_in[7];
  const float* Wr  = (const float*)d_in[8];
  const float* br  = (const float*)d_in[9];
  float* ws = (float*)d_ws;   // needs ~21.4 MB

  k_prep<<<280, 256, 0, stream>>>(Wb, Ws_, Wa, bb, Wz, bz, Wr, ws);

  for (int it = 0; it < NITERS; ++it) {
    uint32_t f0 = 0u, f1 = (uint32_t)it;
    tf2x32(0u, 42u, f0, f1);
    k_actions<<<4500, 256, 0, stream>>>(f0, f1, ws);
    k_roll<<<1000, 256, 0, stream>>>(ws, belief, state, br);
    k_topk<<<16, 1024, 0, stream>>>(ws);
    k_meanstd<<<288, 256, 0, stream>>>(ws);
  }
  k_out<<<1, 128, 0, stream>>>(ws, (float*)d_out);
}